// Round 1
// baseline (156.073 us; speedup 1.0000x reference)
//
#include <hip/hip_runtime.h>
#include <hip/hip_bf16.h>

// MixedScoresSDPA: out = softmax(MLP2(relu(MLP1([QK^T*scale, dmat])))) @ V
// B=8 H=8 M=N=512 D=64 HID=16, all fp32 in/out.
//
// Strategy: flash-attention fused kernel, swapped QK^T (S^T in regs so softmax
// rows are lane-local), bf16 hi/lo split MFMAs for f32-level accuracy
// (no fp32 MFMA on CDNA4), MLP on VALU in exp2 domain (scale & log2e folded,
// b2 dropped via softmax shift invariance).

typedef __attribute__((ext_vector_type(4))) float f32x4;
typedef __attribute__((ext_vector_type(8))) __bf16 bf16x8;
typedef __attribute__((ext_vector_type(4))) unsigned short us4;
typedef __attribute__((ext_vector_type(8))) unsigned short us8;

union U8 { us8 u; bf16x8 b; };

static __device__ __forceinline__ unsigned short bf_hi(float x) {
    unsigned int u = __float_as_uint(x);
    u += 0x7fffu + ((u >> 16) & 1u);   // round-to-nearest-even
    return (unsigned short)(u >> 16);
}
static __device__ __forceinline__ float bf_f(unsigned short s) {
    return __uint_as_float(((unsigned int)s) << 16);
}
static __device__ __forceinline__ float rlf(float x) {   // force SGPR residency
    return __uint_as_float(__builtin_amdgcn_readfirstlane(__float_as_uint(x)));
}

// XOR-swizzled index for [64][64] bf16 tiles: chunk-of-8 ^ (row&7).
// b128 reads at (row, col8) then hit all 32 banks uniformly.
static __device__ __forceinline__ int sw64(int row, int col) {
    return row * 64 + ((((col >> 3) ^ (row & 7)) << 3) | (col & 7));
}
// XOR-swizzled index for [64][64] f32 tile: chunk-of-4 ^ (row&15).
static __device__ __forceinline__ int swdm(int row, int col) {
    return row * 64 + ((((col >> 2) ^ (row & 15)) << 2) | (col & 3));
}

#define B_ 8
#define H_ 8
#define M_ 512
#define N_ 512
#define D_ 64
#define HID_ 16

__global__ __launch_bounds__(256, 2) void msdpa_kernel(
    const float* __restrict__ qg, const float* __restrict__ kg,
    const float* __restrict__ vg, const float* __restrict__ dg,
    const float* __restrict__ w1g, const float* __restrict__ b1g,
    const float* __restrict__ w2g, float* __restrict__ outg)
{
    extern __shared__ f32x4 smem4[];
    unsigned short* KH  = (unsigned short*)smem4;   // K hi   [64n][64d] swz, 8KB
    unsigned short* KL  = KH + 4096;                // K lo
    unsigned short* VTH = KL + 4096;                // V^T hi [64d][64n] swz
    unsigned short* VTL = VTH + 4096;               // V^T lo
    float*          DM  = (float*)(VTL + 4096);     // dmat   [64m][64n] swz, 16KB
    unsigned short* PH  = (unsigned short*)(DM + 4096); // P hi, 4 waves x [16m][64n]
    unsigned short* PL  = PH + 4096;                // P lo          (total 64KB)

    const int tid  = threadIdx.x;
    const int lane = tid & 63;
    const int wv   = tid >> 6;
    const int r16  = lane & 15;
    const int g    = lane >> 4;

    const int bm = blockIdx.x;   // m-tile
    const int h  = blockIdx.y;
    const int b  = blockIdx.z;

    unsigned short* PHw = PH + wv * 1024;
    unsigned short* PLw = PL + wv * 1024;

    // ---- per-head MLP constants (uniform -> SGPRs). scale 1/8 folded into a,
    // log2e folded into w2; b2 dropped (softmax shift-invariant).
    const float* w1h = w1g + h * 2 * HID_;
    const float* b1h = b1g + h * HID_;
    const float* w2h = w2g + h * HID_;
    float ap[HID_], cc[HID_], bb[HID_], wp[HID_];
#pragma unroll
    for (int f = 0; f < HID_; ++f) {
        ap[f] = rlf(w1h[f]) * 0.125f;
        cc[f] = rlf(w1h[HID_ + f]);
        bb[f] = rlf(b1h[f]);
        wp[f] = rlf(w2h[f]) * 1.4426950408889634f;
    }

    // ---- Q fragments for this wave's 16 rows (hi/lo bf16 split), B-operand:
    // lane holds Q[m=lane&15][d = ks*32 + (lane>>4)*8 + j]
    const long bh = (long)(b * H_ + h);
    const float* qbase = qg + (bh * M_ + (long)bm * 64 + wv * 16 + r16) * D_;
    bf16x8 qh[2], ql[2];
#pragma unroll
    for (int ks = 0; ks < 2; ++ks) {
        f32x4 x0 = *(const f32x4*)(qbase + ks * 32 + g * 8);
        f32x4 x1 = *(const f32x4*)(qbase + ks * 32 + g * 8 + 4);
        U8 uh, ul;
#pragma unroll
        for (int j = 0; j < 8; ++j) {
            float xv = (j < 4) ? x0[j] : x1[j - 4];
            unsigned short hs = bf_hi(xv);
            uh.u[j] = hs;
            ul.u[j] = bf_hi(xv - bf_f(hs));
        }
        qh[ks] = uh.b; ql[ks] = ul.b;
    }

    f32x4 oacc[4];
#pragma unroll
    for (int dt = 0; dt < 4; ++dt) oacc[dt] = f32x4{0.f, 0.f, 0.f, 0.f};
    float mrun = -1e30f, lsum = 0.0f;

    const float* kbase = kg + bh * N_ * D_;
    const float* vbase = vg + bh * N_ * D_;
    const float* dbase = dg + ((long)b * M_ + (long)bm * 64) * N_;

    for (int nt = 0; nt < 8; ++nt) {
        const int n0 = nt * 64;
        __syncthreads();   // previous tile's LDS reads done
        // ---- stage K(hi/lo), V^T(hi/lo), dmat
#pragma unroll
        for (int it = 0; it < 4; ++it) {
            int e  = it * 1024 + tid * 4;
            int rr = e >> 6, c0 = e & 63;
            f32x4 kk = *(const f32x4*)(kbase + (long)(n0 + rr) * D_ + c0);
            us4 khs, kls;
#pragma unroll
            for (int i = 0; i < 4; ++i) {
                unsigned short hs = bf_hi(kk[i]);
                khs[i] = hs; kls[i] = bf_hi(kk[i] - bf_f(hs));
            }
            int kidx = sw64(rr, c0);
            *(us4*)(KH + kidx) = khs;
            *(us4*)(KL + kidx) = kls;
            f32x4 vv = *(const f32x4*)(vbase + (long)(n0 + rr) * D_ + c0);
#pragma unroll
            for (int i = 0; i < 4; ++i) {   // transpose scatter (2B) — v1 cost
                unsigned short hs = bf_hi(vv[i]);
                VTH[sw64(c0 + i, rr)] = hs;
                VTL[sw64(c0 + i, rr)] = bf_hi(vv[i] - bf_f(hs));
            }
            f32x4 dd = *(const f32x4*)(dbase + (long)rr * N_ + n0 + c0);
            *(f32x4*)(DM + swdm(rr, c0)) = dd;
        }
        __syncthreads();

        // ---- QK^T (swapped: A=K, B=Q) -> S^T; 3-term hi/lo split
        f32x4 sacc[4];
#pragma unroll
        for (int n16 = 0; n16 < 4; ++n16) sacc[n16] = f32x4{0.f, 0.f, 0.f, 0.f};
#pragma unroll
        for (int n16 = 0; n16 < 4; ++n16) {
            int row = n16 * 16 + r16;
#pragma unroll
            for (int ks = 0; ks < 2; ++ks) {
                int off = sw64(row, ks * 32 + g * 8);
                bf16x8 kh_ = *(bf16x8*)(KH + off);
                bf16x8 kl_ = *(bf16x8*)(KL + off);
                sacc[n16] = __builtin_amdgcn_mfma_f32_16x16x32_bf16(kh_, qh[ks], sacc[n16], 0, 0, 0);
                sacc[n16] = __builtin_amdgcn_mfma_f32_16x16x32_bf16(kh_, ql[ks], sacc[n16], 0, 0, 0);
                sacc[n16] = __builtin_amdgcn_mfma_f32_16x16x32_bf16(kl_, qh[ks], sacc[n16], 0, 0, 0);
            }
        }
        // lane now holds S^T: row m = r16, n = 16*n16 + 4*g + r

        // ---- MLP (f-outer: 16 independent FMA chains)
        const int dmrow = wv * 16 + r16;
        f32x4 dmv[4];
#pragma unroll
        for (int n16 = 0; n16 < 4; ++n16)
            dmv[n16] = *(const f32x4*)(DM + swdm(dmrow, n16 * 16 + g * 4));
        float ms[4][4];
#pragma unroll
        for (int n16 = 0; n16 < 4; ++n16)
#pragma unroll
            for (int r = 0; r < 4; ++r) ms[n16][r] = 0.0f;
#pragma unroll
        for (int f = 0; f < HID_; ++f) {
            float a = ap[f], c = cc[f], bcst = bb[f], w = wp[f];
#pragma unroll
            for (int n16 = 0; n16 < 4; ++n16)
#pragma unroll
                for (int r = 0; r < 4; ++r) {
                    float u = fmaf(a, sacc[n16][r], fmaf(c, dmv[n16][r], bcst));
                    ms[n16][r] = fmaf(w, fmaxf(u, 0.0f), ms[n16][r]);
                }
        }

        // ---- online softmax (rows lane-local; reduce across 4 lane-groups)
        float mloc = -1e30f;
#pragma unroll
        for (int n16 = 0; n16 < 4; ++n16)
#pragma unroll
            for (int r = 0; r < 4; ++r) mloc = fmaxf(mloc, ms[n16][r]);
        mloc = fmaxf(mloc, __shfl_xor(mloc, 16));
        mloc = fmaxf(mloc, __shfl_xor(mloc, 32));
        float mnew = fmaxf(mrun, mloc);
        float sc = exp2f(mrun - mnew);
        mrun = mnew;

        float psum = 0.0f;
#pragma unroll
        for (int n16 = 0; n16 < 4; ++n16) {
            us4 phs, pls;
#pragma unroll
            for (int r = 0; r < 4; ++r) {
                float p = exp2f(ms[n16][r] - mnew);
                psum += p;
                unsigned short hs = bf_hi(p);
                phs[r] = hs;
                pls[r] = bf_hi(p - bf_f(hs));
            }
            int pidx = sw64(r16, n16 * 16 + g * 4);  // row<16 -> same swizzle
            *(us4*)(PHw + pidx) = phs;
            *(us4*)(PLw + pidx) = pls;
        }
        lsum = lsum * sc + psum;

        // ---- rescale O (O rows are m=4g+r; scale lives at lane m)
        float scm[4];
#pragma unroll
        for (int r = 0; r < 4; ++r) scm[r] = __shfl(sc, g * 4 + r);
#pragma unroll
        for (int dt = 0; dt < 4; ++dt)
#pragma unroll
            for (int r = 0; r < 4; ++r) oacc[dt][r] *= scm[r];

        // ---- PV: A=P (from per-wave LDS), B=V^T; 3-term hi/lo split
#pragma unroll
        for (int ks = 0; ks < 2; ++ks) {
            int poff = sw64(r16, ks * 32 + g * 8);
            bf16x8 pa = *(bf16x8*)(PHw + poff);
            bf16x8 pb = *(bf16x8*)(PLw + poff);
#pragma unroll
            for (int dt = 0; dt < 4; ++dt) {
                int voff = sw64(dt * 16 + r16, ks * 32 + g * 8);
                bf16x8 vh_ = *(bf16x8*)(VTH + voff);
                bf16x8 vl_ = *(bf16x8*)(VTL + voff);
                oacc[dt] = __builtin_amdgcn_mfma_f32_16x16x32_bf16(pa, vh_, oacc[dt], 0, 0, 0);
                oacc[dt] = __builtin_amdgcn_mfma_f32_16x16x32_bf16(pa, vl_, oacc[dt], 0, 0, 0);
                oacc[dt] = __builtin_amdgcn_mfma_f32_16x16x32_bf16(pb, vh_, oacc[dt], 0, 0, 0);
            }
        }
    }

    // ---- epilogue: finish row sums, normalize, store
    lsum += __shfl_xor(lsum, 16);
    lsum += __shfl_xor(lsum, 32);
    float linv[4];
#pragma unroll
    for (int r = 0; r < 4; ++r) linv[r] = 1.0f / __shfl(lsum, g * 4 + r);

    float* obase = outg + (bh * M_ + (long)bm * 64 + wv * 16) * D_;
#pragma unroll
    for (int dt = 0; dt < 4; ++dt)
#pragma unroll
        for (int r = 0; r < 4; ++r)
            obase[(g * 4 + r) * D_ + dt * 16 + r16] = oacc[dt][r] * linv[r];
}

extern "C" void kernel_launch(void* const* d_in, const int* in_sizes, int n_in,
                              void* d_out, int out_size, void* d_ws, size_t ws_size,
                              hipStream_t stream) {
    const float* q  = (const float*)d_in[0];
    const float* k  = (const float*)d_in[1];
    const float* v  = (const float*)d_in[2];
    const float* dm = (const float*)d_in[3];
    const float* w1 = (const float*)d_in[4];
    const float* b1 = (const float*)d_in[5];
    const float* w2 = (const float*)d_in[6];
    // d_in[7] = mix_b2: unused (softmax shift-invariant)
    float* out = (float*)d_out;

    (void)hipFuncSetAttribute(reinterpret_cast<const void*>(msdpa_kernel),
                              hipFuncAttributeMaxDynamicSharedMemorySize, 65536);
    dim3 grid(M_ / 64, H_, B_);   // 8 x 8 x 8 = 512 blocks = 2/CU
    msdpa_kernel<<<grid, dim3(256), 65536, stream>>>(q, k, v, dm, w1, b1, w2, out);
}

// Round 3
// 136.696 us; speedup vs baseline: 1.1418x; 1.1418x over previous
//
#include <hip/hip_runtime.h>
#include <hip/hip_bf16.h>

// MixedScoresSDPA: out = softmax(MLP2(relu(MLP1([QK^T*scale, dmat])))) @ V
// B=8 H=8 M=N=512 D=64 HID=16, fp32 in/out.
// r2: tr-read V (no scatter), dmat from global, reg-prefetch K/V, f32x2 packed MLP.
// (resubmitted unchanged after r2 GPU-acquisition timeout)

typedef __attribute__((ext_vector_type(4))) float f32x4;
typedef __attribute__((ext_vector_type(2))) float f32x2;
typedef __attribute__((ext_vector_type(8))) __bf16 bf16x8;
typedef __attribute__((ext_vector_type(4))) __bf16 bf16x4;

static __device__ __forceinline__ float rlf(float x) {   // force SGPR residency
    return __uint_as_float(__builtin_amdgcn_readfirstlane(__float_as_uint(x)));
}
static __device__ __forceinline__ void cvt2(float x, __bf16& h, __bf16& l) {
    h = (__bf16)x;                    // RNE f32->bf16 (compiler may pack v_cvt_pk_bf16_f32)
    l = (__bf16)(x - (float)h);       // residual
}
// XOR-swizzled index for [64][64] bf16 K tiles: chunk-of-8 ^ (row&7) -> conflict-free b128.
static __device__ __forceinline__ int sw64(int row, int col) {
    return row * 64 + ((((col >> 3) ^ (row & 7)) << 3) | (col & 7));
}

// gfx950 LDS transpose read: lane l gets column (l&15) of the 4x16 bf16 subtile
// its 16-lane group addresses (addr_l = subtile_base + (l&15)*8).
template<int OFF>
static __device__ __forceinline__ bf16x4 trrd(unsigned base) {
    bf16x4 d;
    asm volatile("ds_read_b64_tr_b16 %0, %1 offset:%2" : "=v"(d) : "v"(base), "i"(OFF));
    return d;
}

#define B_ 8
#define H_ 8
#define M_ 512
#define N_ 512
#define D_ 64
#define HID_ 16
#define PSTRIDE 68   // P row stride in elems (136B: odd-16 pad -> banks rotate per row)

// PV for one k-half (n in [KS*32, KS*32+32)). P layout chunk swizzle: chunk c at
// row m stored at (c ^ m); V in [n/4][d/16][4][16] subtiles, hi at +0, lo at +8192B.
template<int KS>
static __device__ __forceinline__ void pv_half(unsigned vaddr, const __bf16* PHw,
                                               const __bf16* PLw, int r16, int g,
                                               f32x4* oacc) {
    const int off0 = r16 * PSTRIDE + (((KS * 8)     + g) ^ r16) * 4;
    const int off1 = r16 * PSTRIDE + (((KS * 8) + 4 + g) ^ r16) * 4;
    bf16x4 pa0 = *(const bf16x4*)(PHw + off0);
    bf16x4 pa1 = *(const bf16x4*)(PHw + off1);
    bf16x4 pb0 = *(const bf16x4*)(PLw + off0);
    bf16x4 pb1 = *(const bf16x4*)(PLw + off1);
    bf16x8 pa = __builtin_shufflevector(pa0, pa1, 0, 1, 2, 3, 4, 5, 6, 7);
    bf16x8 pb = __builtin_shufflevector(pb0, pb1, 0, 1, 2, 3, 4, 5, 6, 7);

    bf16x4 h0[4], h1[4], l0[4], l1[4];
#define TRV(arr, BOFF)                      \
    arr[0] = trrd<(BOFF)      >(vaddr);     \
    arr[1] = trrd<(BOFF) + 128>(vaddr);     \
    arr[2] = trrd<(BOFF) + 256>(vaddr);     \
    arr[3] = trrd<(BOFF) + 384>(vaddr);
    TRV(h0, KS * 4096)            // V hi, n-halves 0
    TRV(h1, KS * 4096 + 2048)     // V hi, n-halves 1
    TRV(l0, KS * 4096 + 8192)     // V lo
    TRV(l1, KS * 4096 + 10240)
#undef TRV
    asm volatile("s_waitcnt lgkmcnt(0)" ::: "memory");   // asm reads aren't compiler-tracked
    __builtin_amdgcn_sched_barrier(0);                    // rule 18: pin MFMAs after the wait

#pragma unroll
    for (int dt = 0; dt < 4; ++dt) {
        bf16x8 vh = __builtin_shufflevector(h0[dt], h1[dt], 0, 1, 2, 3, 4, 5, 6, 7);
        bf16x8 vl = __builtin_shufflevector(l0[dt], l1[dt], 0, 1, 2, 3, 4, 5, 6, 7);
        oacc[dt] = __builtin_amdgcn_mfma_f32_16x16x32_bf16(pa, vh, oacc[dt], 0, 0, 0);
        oacc[dt] = __builtin_amdgcn_mfma_f32_16x16x32_bf16(pa, vl, oacc[dt], 0, 0, 0);
        oacc[dt] = __builtin_amdgcn_mfma_f32_16x16x32_bf16(pb, vh, oacc[dt], 0, 0, 0);
    }
}

__global__ __launch_bounds__(256, 2) void msdpa_kernel(
    const float* __restrict__ qg, const float* __restrict__ kg,
    const float* __restrict__ vg, const float* __restrict__ dg,
    const float* __restrict__ w1g, const float* __restrict__ b1g,
    const float* __restrict__ w2g, float* __restrict__ outg)
{
    extern __shared__ __bf16 smem[];
    __bf16* KH = smem;            // K hi  [64n][64d] sw64        8KB
    __bf16* KL = KH + 4096;       // K lo                          8KB
    __bf16* VH = KL + 4096;       // V hi  [n/4][d/16][4][16]      8KB
    __bf16* VL = VH + 4096;       // V lo (must be VH+8192B)       8KB
    __bf16* PH = VL + 4096;       // P hi, 4 waves x [16][PSTRIDE] 8.5KB
    __bf16* PL = PH + 4 * 16 * PSTRIDE;  //                        8.5KB  => 50176B total

    const int tid  = threadIdx.x;
    const int lane = tid & 63;
    const int wv   = tid >> 6;
    const int r16  = lane & 15;
    const int g    = lane >> 4;

    const int bm = blockIdx.x;
    const int h  = blockIdx.y;
    const int b  = blockIdx.z;

    __bf16* PHw = PH + wv * 16 * PSTRIDE;
    __bf16* PLw = PL + wv * 16 * PSTRIDE;

    // per-head MLP constants -> SGPRs. scale 1/8 folded into a, log2e into w2;
    // b2 dropped (softmax shift-invariant).
    const float* w1h = w1g + h * 2 * HID_;
    const float* b1h = b1g + h * HID_;
    const float* w2h = w2g + h * HID_;
    float ap[HID_], cc[HID_], bb[HID_], wp[HID_];
#pragma unroll
    for (int f = 0; f < HID_; ++f) {
        ap[f] = rlf(w1h[f]) * 0.125f;
        cc[f] = rlf(w1h[HID_ + f]);
        bb[f] = rlf(b1h[f]);
        wp[f] = rlf(w2h[f]) * 1.4426950408889634f;
    }

    // Q fragments (hi/lo bf16), B-operand: lane holds Q[m=r16][d = ks*32 + g*8 + j]
    const long bh = (long)(b * H_ + h);
    const float* qbase = qg + (bh * M_ + (long)bm * 64 + wv * 16 + r16) * D_;
    bf16x8 qh[2], ql[2];
#pragma unroll
    for (int ks = 0; ks < 2; ++ks) {
        f32x4 x0 = *(const f32x4*)(qbase + ks * 32 + g * 8);
        f32x4 x1 = *(const f32x4*)(qbase + ks * 32 + g * 8 + 4);
        bf16x8 hv, lv;
#pragma unroll
        for (int j = 0; j < 4; ++j) {
            __bf16 hs, ls;
            cvt2(x0[j], hs, ls); hv[j] = hs; lv[j] = ls;
            cvt2(x1[j], hs, ls); hv[4 + j] = hs; lv[4 + j] = ls;
        }
        qh[ks] = hv; ql[ks] = lv;
    }

    f32x4 oacc[4];
#pragma unroll
    for (int dt = 0; dt < 4; ++dt) oacc[dt] = f32x4{0.f, 0.f, 0.f, 0.f};
    float mrun = -1e30f, lsum = 0.0f;

    const float* kb  = kg + bh * N_ * D_;
    const float* vb  = vg + bh * N_ * D_;
    const float* dmp = dg + ((long)b * M_ + (long)bm * 64 + wv * 16 + r16) * N_ + g * 4;
    const unsigned vhbase = (unsigned)(size_t)VH;   // LDS byte base for tr reads
    const unsigned vaddr  = vhbase + (unsigned)(g * 512 + r16 * 8);
    const int e = tid * 4;   // staging element offset base (it adds 1024)

    // prologue: prefetch tile 0 K/V into registers
    f32x4 kk[4], vv[4];
#pragma unroll
    for (int it = 0; it < 4; ++it) {
        kk[it] = *(const f32x4*)(kb + it * 1024 + e);
        vv[it] = *(const f32x4*)(vb + it * 1024 + e);
    }

    for (int nt = 0; nt < 8; ++nt) {
        const int n0 = nt * 64;
        __syncthreads();   // prev tile's LDS readers done (also drains prefetch vmcnt)
        // ---- stage K (sw64) and V (4x16 subtiles) from prefetched regs
#pragma unroll
        for (int it = 0; it < 4; ++it) {
            const int ee = it * 1024 + e;
            const int rr = ee >> 6, c0 = ee & 63;
            bf16x4 kh4, kl4, vh4, vl4;
#pragma unroll
            for (int i = 0; i < 4; ++i) {
                __bf16 hs, ls;
                cvt2(kk[it][i], hs, ls); kh4[i] = hs; kl4[i] = ls;
                cvt2(vv[it][i], hs, ls); vh4[i] = hs; vl4[i] = ls;
            }
            const int kidx = sw64(rr, c0);
            *(bf16x4*)(KH + kidx) = kh4;
            *(bf16x4*)(KL + kidx) = kl4;
            const int vidx = ((rr >> 2) * 4 + (c0 >> 4)) * 64 + (rr & 3) * 16 + (c0 & 15);
            *(bf16x4*)(VH + vidx) = vh4;
            *(bf16x4*)(VL + vidx) = vl4;
        }
        __syncthreads();

        // ---- prefetch next tile's K/V (latency hidden under QK+MLP+PV)
        if (nt < 7) {
#pragma unroll
            for (int it = 0; it < 4; ++it) {
                kk[it] = *(const f32x4*)(kb + (n0 + 64) * 64 + it * 1024 + e);
                vv[it] = *(const f32x4*)(vb + (n0 + 64) * 64 + it * 1024 + e);
            }
        }
        // ---- dmat for this tile straight from global (L2/L3); QK hides latency
        f32x4 dmv[4];
#pragma unroll
        for (int n16 = 0; n16 < 4; ++n16)
            dmv[n16] = *(const f32x4*)(dmp + n0 + n16 * 16);

        // ---- QK^T (swapped: A=K, B=Q) -> S^T; 3-term hi/lo split
        f32x4 sacc[4];
#pragma unroll
        for (int n16 = 0; n16 < 4; ++n16) sacc[n16] = f32x4{0.f, 0.f, 0.f, 0.f};
#pragma unroll
        for (int n16 = 0; n16 < 4; ++n16) {
            const int row = n16 * 16 + r16;
#pragma unroll
            for (int ks = 0; ks < 2; ++ks) {
                const int off = sw64(row, ks * 32 + g * 8);
                bf16x8 kh_ = *(bf16x8*)(KH + off);
                bf16x8 kl_ = *(bf16x8*)(KL + off);
                sacc[n16] = __builtin_amdgcn_mfma_f32_16x16x32_bf16(kh_, qh[ks], sacc[n16], 0, 0, 0);
                sacc[n16] = __builtin_amdgcn_mfma_f32_16x16x32_bf16(kh_, ql[ks], sacc[n16], 0, 0, 0);
                sacc[n16] = __builtin_amdgcn_mfma_f32_16x16x32_bf16(kl_, qh[ks], sacc[n16], 0, 0, 0);
            }
        }
        // lane holds S^T: m = r16, n = 16*n16 + 4*g + r

        // ---- MLP on f32x2 pairs (v_pk_fma_f32-eligible)
        f32x2 sp[8], dp[8], acc2[8];
#pragma unroll
        for (int n16 = 0; n16 < 4; ++n16) {
            sp[2 * n16]     = f32x2{sacc[n16][0], sacc[n16][1]};
            sp[2 * n16 + 1] = f32x2{sacc[n16][2], sacc[n16][3]};
            dp[2 * n16]     = f32x2{dmv[n16][0], dmv[n16][1]};
            dp[2 * n16 + 1] = f32x2{dmv[n16][2], dmv[n16][3]};
        }
#pragma unroll
        for (int p = 0; p < 8; ++p) acc2[p] = f32x2{0.f, 0.f};
        const f32x2 zz = f32x2{0.f, 0.f};
#pragma unroll
        for (int f = 0; f < HID_; ++f) {
            const f32x2 av = f32x2{ap[f], ap[f]};
            const f32x2 cv = f32x2{cc[f], cc[f]};
            const f32x2 bv = f32x2{bb[f], bb[f]};
            const f32x2 wv2 = f32x2{wp[f], wp[f]};
#pragma unroll
            for (int p = 0; p < 8; ++p) {
                f32x2 u = cv * dp[p] + bv;
                u = av * sp[p] + u;
                u = __builtin_elementwise_max(u, zz);
                acc2[p] = wv2 * u + acc2[p];
            }
        }

        // ---- online softmax (rows lane-local; reduce across 4 lane-groups)
        f32x2 mx = acc2[0];
#pragma unroll
        for (int p = 1; p < 8; ++p) mx = __builtin_elementwise_max(mx, acc2[p]);
        float mloc = fmaxf(mx[0], mx[1]);
        mloc = fmaxf(mloc, __shfl_xor(mloc, 16));
        mloc = fmaxf(mloc, __shfl_xor(mloc, 32));
        const float mnew = fmaxf(mrun, mloc);
        const float sc = exp2f(mrun - mnew);
        mrun = mnew;

        float psum = 0.0f;
#pragma unroll
        for (int n16 = 0; n16 < 4; ++n16) {
            bf16x4 ph4, pl4;
#pragma unroll
            for (int r = 0; r < 4; ++r) {
                const float p = exp2f(acc2[2 * n16 + (r >> 1)][r & 1] - mnew);
                psum += p;
                __bf16 hs, ls;
                cvt2(p, hs, ls);
                ph4[r] = hs; pl4[r] = ls;
            }
            const int c = (n16 * 4 + g) ^ r16;           // chunk swizzle (matches pv_half)
            const int off = r16 * PSTRIDE + c * 4;
            *(bf16x4*)(PHw + off) = ph4;
            *(bf16x4*)(PLw + off) = pl4;
        }
        lsum = lsum * sc + psum;

        // ---- rescale O (O rows are m=4g+r; scale lives at lane m)
        float scm[4];
#pragma unroll
        for (int r = 0; r < 4; ++r) scm[r] = __shfl(sc, g * 4 + r);
#pragma unroll
        for (int dt = 0; dt < 4; ++dt)
#pragma unroll
            for (int r = 0; r < 4; ++r) oacc[dt][r] *= scm[r];

        // ---- PV via tr-read V fragments (k-permutation matched to P layout)
        pv_half<0>(vaddr, PHw, PLw, r16, g, oacc);
        pv_half<1>(vaddr, PHw, PLw, r16, g, oacc);
    }

    // ---- epilogue
    lsum += __shfl_xor(lsum, 16);
    lsum += __shfl_xor(lsum, 32);
    float linv[4];
#pragma unroll
    for (int r = 0; r < 4; ++r) linv[r] = 1.0f / __shfl(lsum, g * 4 + r);

    float* obase = outg + (bh * M_ + (long)bm * 64 + wv * 16) * D_;
#pragma unroll
    for (int dt = 0; dt < 4; ++dt)
#pragma unroll
        for (int r = 0; r < 4; ++r)
            obase[(g * 4 + r) * D_ + dt * 16 + r16] = oacc[dt][r] * linv[r];
}

extern "C" void kernel_launch(void* const* d_in, const int* in_sizes, int n_in,
                              void* d_out, int out_size, void* d_ws, size_t ws_size,
                              hipStream_t stream) {
    const float* q  = (const float*)d_in[0];
    const float* k  = (const float*)d_in[1];
    const float* v  = (const float*)d_in[2];
    const float* dm = (const float*)d_in[3];
    const float* w1 = (const float*)d_in[4];
    const float* b1 = (const float*)d_in[5];
    const float* w2 = (const float*)d_in[6];
    // d_in[7] = mix_b2: unused (softmax shift-invariant)
    float* out = (float*)d_out;

    (void)hipFuncSetAttribute(reinterpret_cast<const void*>(msdpa_kernel),
                              hipFuncAttributeMaxDynamicSharedMemorySize, 65536);
    dim3 grid(M_ / 64, H_, B_);   // 512 blocks = 2/CU
    msdpa_kernel<<<grid, dim3(256), 50176, stream>>>(q, k, v, dm, w1, b1, w2, out);
}

// Round 4
// 132.595 us; speedup vs baseline: 1.1771x; 1.0309x over previous
//
#include <hip/hip_runtime.h>
#include <hip/hip_bf16.h>

// MixedScoresSDPA: out = softmax(MLP2(relu(MLP1([QK^T*scale, dmat])))) @ V
// B=8 H=8 M=N=512 D=64 HID=16, fp32 in/out.
// r4: prep kernel writes swizzled bf16 hi/lo K and V^T tile images to ws;
//     main kernel stages via global_load_lds (no cvt VALU, no tr-reads, all
//     LDS accesses conflict-free by construction); MLP relu->abs trick.

typedef __attribute__((ext_vector_type(4))) float f32x4;
typedef __attribute__((ext_vector_type(8))) __bf16 bf16x8;
typedef __attribute__((ext_vector_type(4))) __bf16 bf16x4;

static __device__ __forceinline__ float rlf(float x) {   // force SGPR residency
    return __uint_as_float(__builtin_amdgcn_readfirstlane(__float_as_uint(x)));
}
static __device__ __forceinline__ void cvt2(float x, __bf16& h, __bf16& l) {
    h = (__bf16)x;                    // RNE f32->bf16
    l = (__bf16)(x - (float)h);       // residual
}
// XOR-swizzled index for [64][64] bf16 tiles: chunk-of-8 ^ (row&7) -> conflict-free b128.
static __device__ __forceinline__ int sw64(int row, int col) {
    return row * 64 + ((((col >> 3) ^ (row & 7)) << 3) | (col & 7));
}
// async global->LDS, 16B per lane (dest = wave-uniform base + lane*16, lane-linear here)
static __device__ __forceinline__ void dma16(const __bf16* g, __bf16* l) {
    __builtin_amdgcn_global_load_lds(
        (const __attribute__((address_space(1))) unsigned*)g,
        (__attribute__((address_space(3))) unsigned*)l, 16, 0, 0);
}

#define B_ 8
#define H_ 8
#define M_ 512
#define N_ 512
#define D_ 64
#define HID_ 16

// ---------------- prep: K -> (KH,KL) sw64 images; V -> (VTH,VTL) transposed sw64 images.
// ws layout per (bh,nt) [512 tiles]: 16384 bf16 = {KH,KL,VTH,VTL} x 4096 elems.
__global__ __launch_bounds__(256) void prep_kernel(
    const float* __restrict__ kg, const float* __restrict__ vg,
    __bf16* __restrict__ ws)
{
    __shared__ float vld[64 * 68];   // V tile f32, padded stride 68 (16B-aligned rows)
    const int t   = threadIdx.x;
    const int blk = blockIdx.x;                   // bh*8 + nt
    const long base = (long)blk * 4096;           // element offset of this 64x64 tile
    __bf16* out = ws + (long)blk * 16384;

    // stage V tile into LDS (row-major, padded)
#pragma unroll
    for (int it = 0; it < 4; ++it) {
        const int e = it * 1024 + t * 4;
        const int rr = e >> 6, c0 = e & 63;
        f32x4 v4 = *(const f32x4*)(vg + base + e);
        *(f32x4*)(vld + rr * 68 + c0) = v4;
    }

    // K images (straight from global; row-major with chunk pre-swizzle)
#pragma unroll
    for (int qq = t; qq < 512; qq += 256) {
        const int row = qq >> 3, c = qq & 7;
        const float* src = kg + base + row * 64 + ((c ^ (row & 7)) << 3);
        f32x4 a = *(const f32x4*)src;
        f32x4 b4 = *(const f32x4*)(src + 4);
        bf16x8 hv, lv;
#pragma unroll
        for (int j = 0; j < 4; ++j) {
            __bf16 h, l;
            cvt2(a[j], h, l);  hv[j] = h;     lv[j] = l;
            cvt2(b4[j], h, l); hv[4 + j] = h; lv[4 + j] = l;
        }
        *(bf16x8*)(out + qq * 8) = hv;            // KH
        *(bf16x8*)(out + 4096 + qq * 8) = lv;     // KL
    }
    __syncthreads();

    // V^T images: image(d, c*8+j) = V[((c^(d&7))*8+j)][d]
#pragma unroll
    for (int qq = t; qq < 512; qq += 256) {
        const int d = qq & 63, c = qq >> 6;       // d-major across lanes: LDS conflict-free
        bf16x8 hv, lv;
#pragma unroll
        for (int j = 0; j < 8; ++j) {
            const int n = ((c ^ (d & 7)) << 3) + j;
            __bf16 h, l;
            cvt2(vld[n * 68 + d], h, l);
            hv[j] = h; lv[j] = l;
        }
        const int pos = d * 64 + c * 8;
        *(bf16x8*)(out + 8192 + pos) = hv;        // VTH
        *(bf16x8*)(out + 12288 + pos) = lv;       // VTL
    }
}

// ---------------- main kernel
__global__ __launch_bounds__(256, 2) void msdpa_kernel(
    const float* __restrict__ qg, const __bf16* __restrict__ ws,
    const float* __restrict__ dg, const float* __restrict__ w1g,
    const float* __restrict__ b1g, const float* __restrict__ w2g,
    float* __restrict__ outg)
{
    extern __shared__ __bf16 smem[];
    // KH 0, KL 4096, VTH 8192, VTL 12288 | PH 16384 (+wv*1024), PL 20480 (+wv*1024)
    __bf16* KH  = smem;
    __bf16* KL  = smem + 4096;
    __bf16* VTH = smem + 8192;
    __bf16* VTL = smem + 12288;

    const int tid  = threadIdx.x;
    const int lane = tid & 63;
    const int wv   = tid >> 6;
    const int r16  = lane & 15;
    const int g    = lane >> 4;

    const int bm = blockIdx.x;
    const int h  = blockIdx.y;
    const int b  = blockIdx.z;

    __bf16* PHw = smem + 16384 + wv * 1024;   // [16][64] chunk-swizzled
    __bf16* PLw = smem + 20480 + wv * 1024;

    // per-head MLP constants -> SGPRs. scale 1/8 folded into af, log2e*0.5 into wa;
    // b2 dropped (softmax shift-invariant). relu(u) = (u+|u|)/2 ->
    // mixed*log2e = (A*s + C*d + B0) + sum_f wa_f * |u_f|
    const float* w1h = w1g + h * 2 * HID_;
    const float* b1h = b1g + h * HID_;
    const float* w2h = w2g + h * HID_;
    float af[HID_], cf[HID_], bf_[HID_], wa[HID_];
    float A = 0.f, C = 0.f, B0 = 0.f;
#pragma unroll
    for (int f = 0; f < HID_; ++f) {
        af[f] = rlf(w1h[f]) * 0.125f;
        cf[f] = rlf(w1h[HID_ + f]);
        bf_[f] = rlf(b1h[f]);
        wa[f] = rlf(w2h[f]) * (1.4426950408889634f * 0.5f);
        A  = fmaf(wa[f], af[f], A);
        C  = fmaf(wa[f], cf[f], C);
        B0 = fmaf(wa[f], bf_[f], B0);
    }

    // Q fragments (hi/lo bf16), B-operand: lane holds Q[m=r16][d = ks*32 + g*8 + j]
    const long bh = (long)(b * H_ + h);
    const float* qbase = qg + (bh * M_ + (long)bm * 64 + wv * 16 + r16) * D_;
    bf16x8 qh[2], ql[2];
#pragma unroll
    for (int ks = 0; ks < 2; ++ks) {
        f32x4 x0 = *(const f32x4*)(qbase + ks * 32 + g * 8);
        f32x4 x1 = *(const f32x4*)(qbase + ks * 32 + g * 8 + 4);
        bf16x8 hv, lv;
#pragma unroll
        for (int j = 0; j < 4; ++j) {
            __bf16 h_, l_;
            cvt2(x0[j], h_, l_); hv[j] = h_; lv[j] = l_;
            cvt2(x1[j], h_, l_); hv[4 + j] = h_; lv[4 + j] = l_;
        }
        qh[ks] = hv; ql[ks] = lv;
    }

    f32x4 oacc[4];
#pragma unroll
    for (int dt = 0; dt < 4; ++dt) oacc[dt] = f32x4{0.f, 0.f, 0.f, 0.f};
    float mrun = -1e30f, lsum = 0.0f;

    const __bf16* wsbh = ws + bh * (8L * 16384);
    const float* dmp = dg + ((long)b * M_ + (long)bm * 64 + wv * 16 + r16) * N_ + g * 4;

    for (int nt = 0; nt < 8; ++nt) {
        __syncthreads();   // all waves done reading previous tile
        // ---- stage {KH,KL,VTH,VTL} images via async DMA (no VALU, no conflicts)
        const __bf16* tile = wsbh + nt * 16384;
#pragma unroll
        for (int i = 0; i < 8; ++i)
            dma16(tile + i * 2048 + tid * 8, smem + i * 2048 + tid * 8);
        __syncthreads();   // compiler emits vmcnt(0) before s_barrier -> staged

        // ---- dmat for this tile straight from global (L2/L3-resident)
        f32x4 dmv[4];
#pragma unroll
        for (int n16 = 0; n16 < 4; ++n16)
            dmv[n16] = *(const f32x4*)(dmp + nt * 64 + n16 * 16);

        // ---- QK^T (swapped: A=K, B=Q) -> S^T; 3-term hi/lo split
        f32x4 sacc[4];
#pragma unroll
        for (int n16 = 0; n16 < 4; ++n16) sacc[n16] = f32x4{0.f, 0.f, 0.f, 0.f};
#pragma unroll
        for (int n16 = 0; n16 < 4; ++n16) {
            const int row = n16 * 16 + r16;
#pragma unroll
            for (int ks = 0; ks < 2; ++ks) {
                const int off = sw64(row, ks * 32 + g * 8);
                bf16x8 kh_ = *(const bf16x8*)(KH + off);
                bf16x8 kl_ = *(const bf16x8*)(KL + off);
                sacc[n16] = __builtin_amdgcn_mfma_f32_16x16x32_bf16(kh_, qh[ks], sacc[n16], 0, 0, 0);
                sacc[n16] = __builtin_amdgcn_mfma_f32_16x16x32_bf16(kh_, ql[ks], sacc[n16], 0, 0, 0);
                sacc[n16] = __builtin_amdgcn_mfma_f32_16x16x32_bf16(kl_, qh[ks], sacc[n16], 0, 0, 0);
            }
        }
        // lane holds S^T: m = r16, n = 16*n16 + 4*g + r

        // ---- MLP via relu->abs: ms = A*s + C*d + B0 + sum_f wa_f*|af_f*s + cf_f*d + bf_f|
        float ms[4][4];
#pragma unroll
        for (int n16 = 0; n16 < 4; ++n16)
#pragma unroll
            for (int r = 0; r < 4; ++r) {
                const float s = sacc[n16][r], d = dmv[n16][r];
                float acc = fmaf(A, s, fmaf(C, d, B0));
#pragma unroll
                for (int f = 0; f < HID_; ++f) {
                    const float u = fmaf(af[f], s, fmaf(cf[f], d, bf_[f]));
                    acc = fmaf(wa[f], fabsf(u), acc);   // |u| free via VOP3 abs modifier
                }
                ms[n16][r] = acc;
            }

        // ---- online softmax (rows lane-local; reduce across 4 lane-groups)
        float mloc = -1e30f;
#pragma unroll
        for (int n16 = 0; n16 < 4; ++n16)
#pragma unroll
            for (int r = 0; r < 4; ++r) mloc = fmaxf(mloc, ms[n16][r]);
        mloc = fmaxf(mloc, __shfl_xor(mloc, 16));
        mloc = fmaxf(mloc, __shfl_xor(mloc, 32));
        const float mnew = fmaxf(mrun, mloc);
        const float sc = exp2f(mrun - mnew);
        mrun = mnew;

        float psum = 0.0f;
#pragma unroll
        for (int n16 = 0; n16 < 4; ++n16) {
            bf16x4 ph4, pl4;
#pragma unroll
            for (int r = 0; r < 4; ++r) {
                const float p = exp2f(ms[n16][r] - mnew);
                psum += p;
                __bf16 h_, l_;
                cvt2(p, h_, l_);
                ph4[r] = h_; pl4[r] = l_;
            }
            // 8-elem chunk cc stored at chunk cc^(r16&7); this 4-group is half (g&1)
            const int cc = 2 * n16 + (g >> 1);
            const int pos = r16 * 64 + (((cc ^ (r16 & 7)) << 3) | ((g & 1) << 2));
            *(bf16x4*)(PHw + pos) = ph4;
            *(bf16x4*)(PLw + pos) = pl4;
        }
        lsum = lsum * sc + psum;

        // ---- rescale O (O rows are m=4g+r; scale lives at lane m)
        float scm[4];
#pragma unroll
        for (int r = 0; r < 4; ++r) scm[r] = __shfl(sc, g * 4 + r);
#pragma unroll
        for (int dt = 0; dt < 4; ++dt)
#pragma unroll
            for (int r = 0; r < 4; ++r) oacc[dt][r] *= scm[r];

        // ---- PV: A=P (b128, chunk ks*4+g), B=V^T (b128 sw64); 3-term hi/lo split
#pragma unroll
        for (int ks = 0; ks < 2; ++ks) {
            const int pofs = r16 * 64 + ((((ks * 4 + g)) ^ (r16 & 7)) << 3);
            bf16x8 pa = *(const bf16x8*)(PHw + pofs);
            bf16x8 pb = *(const bf16x8*)(PLw + pofs);
#pragma unroll
            for (int dt = 0; dt < 4; ++dt) {
                const int vofs = sw64(dt * 16 + r16, ks * 32 + g * 8);
                bf16x8 vh = *(const bf16x8*)(VTH + vofs);
                bf16x8 vl = *(const bf16x8*)(VTL + vofs);
                oacc[dt] = __builtin_amdgcn_mfma_f32_16x16x32_bf16(pa, vh, oacc[dt], 0, 0, 0);
                oacc[dt] = __builtin_amdgcn_mfma_f32_16x16x32_bf16(pa, vl, oacc[dt], 0, 0, 0);
                oacc[dt] = __builtin_amdgcn_mfma_f32_16x16x32_bf16(pb, vh, oacc[dt], 0, 0, 0);
            }
        }
    }

    // ---- epilogue
    lsum += __shfl_xor(lsum, 16);
    lsum += __shfl_xor(lsum, 32);
    float linv[4];
#pragma unroll
    for (int r = 0; r < 4; ++r) linv[r] = 1.0f / __shfl(lsum, g * 4 + r);

    float* obase = outg + (bh * M_ + (long)bm * 64 + wv * 16) * D_;
#pragma unroll
    for (int dt = 0; dt < 4; ++dt)
#pragma unroll
        for (int r = 0; r < 4; ++r)
            obase[(g * 4 + r) * D_ + dt * 16 + r16] = oacc[dt][r] * linv[r];
}

extern "C" void kernel_launch(void* const* d_in, const int* in_sizes, int n_in,
                              void* d_out, int out_size, void* d_ws, size_t ws_size,
                              hipStream_t stream) {
    const float* q  = (const float*)d_in[0];
    const float* k  = (const float*)d_in[1];
    const float* v  = (const float*)d_in[2];
    const float* dm = (const float*)d_in[3];
    const float* w1 = (const float*)d_in[4];
    const float* b1 = (const float*)d_in[5];
    const float* w2 = (const float*)d_in[6];
    // d_in[7] = mix_b2: unused (softmax shift-invariant)
    float* out = (float*)d_out;
    __bf16* ws = (__bf16*)d_ws;   // needs 512*16384*2B = 16.8 MB

    prep_kernel<<<dim3(512), dim3(256), 0, stream>>>(k, v, ws);

    (void)hipFuncSetAttribute(reinterpret_cast<const void*>(msdpa_kernel),
                              hipFuncAttributeMaxDynamicSharedMemorySize, 65536);
    dim3 grid(M_ / 64, H_, B_);   // 512 blocks = 2/CU
    msdpa_kernel<<<grid, dim3(256), 49152, stream>>>(q, ws, dm, w1, b1, w2, out);
}